// Round 1
// baseline (153.492 us; speedup 1.0000x reference)
//
#include <hip/hip_runtime.h>

#define NPROTO 512
#define NBLK 8
#define DB 128
#define DM 1024
#define TM 128          // query rows per workgroup
#define PC 128          // prototypes per chunk
#define NCHUNK 4
#define LSTR 132        // padded LDS stride (f32 elems)

#define EMB_SIZE 8388608
#define IDX_OFF  8388608
#define VQ_OFF   8454144
#define CL_OFF   8454145

__global__ __launch_bounds__(256) void vq_init(const float* __restrict__ mem,
                                               float* __restrict__ cn) {
    int p = blockIdx.x * 256 + threadIdx.x;   // 0..4095
    const float* c = mem + (size_t)p * DB;
    float s = 0.f;
    #pragma unroll 8
    for (int k = 0; k < DB; k += 4) {
        float4 v = *(const float4*)(c + k);
        s += v.x * v.x + v.y * v.y + v.z * v.z + v.w * v.w;
    }
    cn[p] = s;
}

__global__ __launch_bounds__(256, 1) void vq_main(const float* __restrict__ q,
                                                  const float* __restrict__ mem,
                                                  const float* __restrict__ cn,
                                                  float* __restrict__ out,
                                                  float* __restrict__ partials) {
    __shared__ float q_lds[TM * LSTR];
    __shared__ float c_lds[PC * LSTR];
    __shared__ float qn_lds[TM];
    __shared__ float red[256];

    const int t    = threadIdx.x;
    const int tile = blockIdx.x;   // 0..63
    const int m    = blockIdx.y;   // 0..7
    const int tr   = t >> 4;       // 0..15 (row group)
    const int tc   = t & 15;       // 0..15 (proto group)

    const int bn0 = tile * TM;

    // ---- stage Q tile: 128 rows x 128 cols ----
    const float* qbase = q + (size_t)bn0 * DM + m * DB;
    #pragma unroll
    for (int it = 0; it < 16; ++it) {
        int idx = it * 256 + t;
        int row = idx >> 5;
        int c4  = (idx & 31) << 2;
        float4 v = *(const float4*)(qbase + (size_t)row * DM + c4);
        *(float4*)&q_lds[row * LSTR + c4] = v;
    }
    __syncthreads();

    // ---- qn per row ----
    if (t < TM) {
        const float* r = &q_lds[t * LSTR];
        float s = 0.f;
        #pragma unroll 8
        for (int k = 0; k < DB; k += 4) {
            float4 v = *(const float4*)(r + k);
            s += v.x * v.x + v.y * v.y + v.z * v.z + v.w * v.w;
        }
        qn_lds[t] = s;
    }

    float bestv[8];
    int   besti[8];
    #pragma unroll
    for (int i = 0; i < 8; ++i) { bestv[i] = 3.4e38f; besti[i] = 0; }

    const float* cbase = mem + (size_t)m * NPROTO * DB;

    for (int ch = 0; ch < NCHUNK; ++ch) {
        __syncthreads();
        // ---- stage codes chunk: 128 protos x 128 d ----
        const float* cb = cbase + (size_t)ch * PC * DB;
        #pragma unroll
        for (int it = 0; it < 16; ++it) {
            int idx = it * 256 + t;
            int row = idx >> 5;
            int c4  = (idx & 31) << 2;
            float4 v = *(const float4*)(cb + row * DB + c4);
            *(float4*)&c_lds[row * LSTR + c4] = v;
        }
        __syncthreads();

        float acc[8][8];
        #pragma unroll
        for (int i = 0; i < 8; ++i)
            #pragma unroll
            for (int j = 0; j < 8; ++j) acc[i][j] = 0.f;

        for (int d4 = 0; d4 < DB; d4 += 4) {
            float4 qa[8], cv[8];
            #pragma unroll
            for (int i = 0; i < 8; ++i)
                qa[i] = *(const float4*)&q_lds[(tr + 16 * i) * LSTR + d4];
            #pragma unroll
            for (int j = 0; j < 8; ++j)
                cv[j] = *(const float4*)&c_lds[(tc + 16 * j) * LSTR + d4];
            #pragma unroll
            for (int i = 0; i < 8; ++i) {
                #pragma unroll
                for (int j = 0; j < 8; ++j) {
                    acc[i][j] += qa[i].x * cv[j].x;
                    acc[i][j] += qa[i].y * cv[j].y;
                    acc[i][j] += qa[i].z * cv[j].z;
                    acc[i][j] += qa[i].w * cv[j].w;
                }
            }
        }

        // ---- fold into running argmin ----
        float cnv[8];
        #pragma unroll
        for (int j = 0; j < 8; ++j)
            cnv[j] = cn[m * NPROTO + ch * PC + tc + 16 * j];
        #pragma unroll
        for (int i = 0; i < 8; ++i) {
            float qnr = qn_lds[tr + 16 * i];
            #pragma unroll
            for (int j = 0; j < 8; ++j) {
                int lp = ch * PC + tc + 16 * j;
                float dist = (qnr - 2.0f * acc[i][j]) + cnv[j];
                if (dist < bestv[i]) { bestv[i] = dist; besti[i] = lp; }
            }
        }
    }

    // ---- reduce argmin across the 16 proto-group lanes (same wave) ----
    #pragma unroll
    for (int i = 0; i < 8; ++i) {
        float v = bestv[i]; int ix = besti[i];
        #pragma unroll
        for (int off = 1; off < 16; off <<= 1) {
            float v2 = __shfl_xor(v, off, 64);
            int  ix2 = __shfl_xor(ix, off, 64);
            if (v2 < v || (v2 == v && ix2 < ix)) { v = v2; ix = ix2; }
        }
        bestv[i] = v; besti[i] = ix;
    }

    // ---- epilogue: write emb (exact code copy), indices, loss partial ----
    float lacc = 0.f;
    #pragma unroll
    for (int i = 0; i < 8; ++i) {
        int row = tr + 16 * i;
        int bn  = bn0 + row;
        const float* cvec = cbase + (size_t)besti[i] * DB;
        float* orow = out + (size_t)bn * DM + m * DB;
        #pragma unroll
        for (int h = 0; h < 2; ++h) {
            int col = h * 64 + tc * 4;
            float4 c4v = *(const float4*)(cvec + col);
            *(float4*)(orow + col) = c4v;
            float4 qv = *(const float4*)&q_lds[row * LSTR + col];
            float dx = c4v.x - qv.x, dy = c4v.y - qv.y;
            float dz = c4v.z - qv.z, dw = c4v.w - qv.w;
            lacc += dx * dx + dy * dy + dz * dz + dw * dw;
        }
        if (tc == 0)
            out[(size_t)IDX_OFF + (size_t)bn * NBLK + m] = (float)(m * NPROTO + besti[i]);
    }

    red[t] = lacc;
    __syncthreads();
    for (int s = 128; s > 0; s >>= 1) {
        if (t < s) red[t] += red[t + s];
        __syncthreads();
    }
    if (t == 0) partials[blockIdx.y * gridDim.x + blockIdx.x] = red[0];
}

__global__ __launch_bounds__(256) void vq_final(const float* __restrict__ partials,
                                                float* __restrict__ out) {
    __shared__ float red[256];
    int t = threadIdx.x;
    red[t] = partials[t] + partials[t + 256];
    __syncthreads();
    for (int s = 128; s > 0; s >>= 1) {
        if (t < s) red[t] += red[t + s];
        __syncthreads();
    }
    if (t == 0) {
        out[VQ_OFF] = 0.f;
        out[CL_OFF] = red[0] / 8388608.0f;
    }
}

extern "C" void kernel_launch(void* const* d_in, const int* in_sizes, int n_in,
                              void* d_out, int out_size, void* d_ws, size_t ws_size,
                              hipStream_t stream) {
    const float* q   = (const float*)d_in[0];
    const float* mem = (const float*)d_in[1];
    float* out = (float*)d_out;
    float* cn       = (float*)d_ws;          // 4096 f32
    float* partials = cn + 4096;             // 512 f32

    vq_init<<<16, 256, 0, stream>>>(mem, cn);
    dim3 grid(64, 8);
    vq_main<<<grid, 256, 0, stream>>>(q, mem, cn, out, partials);
    vq_final<<<1, 256, 0, stream>>>(partials, out);
}

// Round 2
// 94.059 us; speedup vs baseline: 1.6319x; 1.6319x over previous
//
#include <hip/hip_runtime.h>

#define NPROTO 512
#define NBLK 8
#define DB 128
#define DM 1024
#define TM 128          // query rows per block
#define PC 128          // protos per chunk
#define LSTR 40         // LDS bf16 stride (32 + 8 pad) -> 80B, 16B-aligned rows

#define N_TOK 8192
#define EMB_SIZE 8388608
#define IDX_OFF  8388608
#define VQ_OFF   8454144
#define CL_OFF   8454145

// ---- ws layout (bytes) ----
#define QHI_B 0u
#define QMI_B (QHI_B + 16777216u)
#define QLO_B (QMI_B + 16777216u)
#define CHI_B (QLO_B + 16777216u)
#define CMI_B (CHI_B + 1048576u)
#define CLO_B (CMI_B + 1048576u)
#define CN_B  (CLO_B + 1048576u)
#define PART_B (CN_B + 16384u)
#define WS_NEED (PART_B + 4096u)

typedef unsigned short u16;
typedef __attribute__((ext_vector_type(8))) short bf16x8;
typedef __attribute__((ext_vector_type(4))) float f32x4;

__device__ __forceinline__ u16 f2bf(float x) {
    unsigned u = __float_as_uint(x);
    unsigned r = (u + 0x7FFFu + ((u >> 16) & 1u)) >> 16;   // RNE
    return (u16)r;
}
__device__ __forceinline__ float bf2f(u16 h) {
    return __uint_as_float(((unsigned)h) << 16);
}

// ---- split a f32 array into 3 bf16 planes (hi/mid/lo) ----
__global__ __launch_bounds__(256) void split_planes(const float* __restrict__ src,
                                                    u16* __restrict__ p0,
                                                    u16* __restrict__ p1,
                                                    u16* __restrict__ p2) {
    size_t i = (size_t)blockIdx.x * 256 + threadIdx.x;   // float4 index
    float4 v = ((const float4*)src)[i];
    ushort4 a, b, c;
    float x, r;
    #define SPLIT1(comp, fld) \
        x = v.comp; a.fld = f2bf(x); r = x - bf2f(a.fld); \
        b.fld = f2bf(r); r = r - bf2f(b.fld); c.fld = f2bf(r);
    SPLIT1(x, x) SPLIT1(y, y) SPLIT1(z, z) SPLIT1(w, w)
    #undef SPLIT1
    ((ushort4*)p0)[i] = a;
    ((ushort4*)p1)[i] = b;
    ((ushort4*)p2)[i] = c;
}

// ---- per-proto squared norms (exact f32) ----
__global__ __launch_bounds__(256) void vq_init(const float* __restrict__ mem,
                                               float* __restrict__ cn) {
    int p = blockIdx.x * 256 + threadIdx.x;   // 0..4095
    const float* c = mem + (size_t)p * DB;
    float s = 0.f;
    #pragma unroll 8
    for (int k = 0; k < DB; k += 4) {
        float4 v = *(const float4*)(c + k);
        s += v.x * v.x + v.y * v.y + v.z * v.z + v.w * v.w;
    }
    cn[p] = s;
}

// ================= MFMA main kernel =================
__global__ __launch_bounds__(256, 2) void vq_main_mfma(
        const float* __restrict__ q, const float* __restrict__ mem,
        const u16* __restrict__ qh, const u16* __restrict__ qm, const u16* __restrict__ ql,
        const u16* __restrict__ ch_, const u16* __restrict__ cm_, const u16* __restrict__ cl_,
        const float* __restrict__ cn, float* __restrict__ out,
        float* __restrict__ partials) {
    __shared__ u16 Aq[3][TM][LSTR];     // 30720 B
    __shared__ u16 Bc[3][PC][LSTR];     // 30720 B
    __shared__ float cnl[PC];
    __shared__ float vbuf[TM];
    __shared__ int   ibuf[TM];
    __shared__ int   bp[TM];
    __shared__ float red[256];

    const int t    = threadIdx.x;
    const int lane = t & 63;
    const int w    = t >> 6;
    const int wr   = w >> 1;          // wave row half (rows wr*64..)
    const int wc   = w & 1;           // wave proto half
    const int lrow = lane & 15;
    const int lk   = lane >> 4;
    const int tile = blockIdx.x;      // 0..63
    const int m    = blockIdx.y;      // 0..7
    const int bn0  = tile * TM;

    const u16* qpl[3] = {qh, qm, ql};
    const u16* cpl[3] = {ch_, cm_, cl_};

    float bestv[4][4];
    int   besti[4][4];
    #pragma unroll
    for (int fi = 0; fi < 4; ++fi)
        #pragma unroll
        for (int r = 0; r < 4; ++r) { bestv[fi][r] = 3.4e38f; besti[fi][r] = 0; }

    for (int ch = 0; ch < 4; ++ch) {
        f32x4 acc[4][4];
        #pragma unroll
        for (int fi = 0; fi < 4; ++fi)
            #pragma unroll
            for (int fj = 0; fj < 4; ++fj)
                #pragma unroll
                for (int r = 0; r < 4; ++r) acc[fi][fj][r] = 0.f;

        for (int s = 0; s < 4; ++s) {
            __syncthreads();
            // ---- stage 6 planes: [128 rows][32 d] each ----
            #pragma unroll
            for (int pl = 0; pl < 3; ++pl) {
                #pragma unroll
                for (int it = 0; it < 2; ++it) {
                    int idx = it * 256 + t;          // 0..511
                    int row = idx >> 2;
                    int g   = idx & 3;
                    uint4 v = *(const uint4*)(qpl[pl] +
                        (size_t)(bn0 + row) * DM + m * DB + s * 32 + g * 8);
                    *(uint4*)&Aq[pl][row][g * 8] = v;
                }
                #pragma unroll
                for (int it = 0; it < 2; ++it) {
                    int idx = it * 256 + t;
                    int row = idx >> 2;
                    int g   = idx & 3;
                    uint4 v = *(const uint4*)(cpl[pl] +
                        (size_t)(m * NPROTO + ch * PC + row) * DB + s * 32 + g * 8);
                    *(uint4*)&Bc[pl][row][g * 8] = v;
                }
            }
            if (s == 0 && t < PC) cnl[t] = cn[m * NPROTO + ch * PC + t];
            __syncthreads();

            // ---- one K=32 step ----
            bf16x8 A0[4], A1[4], A2[4];
            #pragma unroll
            for (int fi = 0; fi < 4; ++fi) {
                int rowa = wr * 64 + fi * 16 + lrow;
                A0[fi] = *(const bf16x8*)&Aq[0][rowa][lk * 8];
                A1[fi] = *(const bf16x8*)&Aq[1][rowa][lk * 8];
                A2[fi] = *(const bf16x8*)&Aq[2][rowa][lk * 8];
            }
            #pragma unroll
            for (int fj = 0; fj < 4; ++fj) {
                int rowb = wc * 64 + fj * 16 + lrow;
                bf16x8 B0 = *(const bf16x8*)&Bc[0][rowb][lk * 8];
                bf16x8 B1 = *(const bf16x8*)&Bc[1][rowb][lk * 8];
                bf16x8 B2 = *(const bf16x8*)&Bc[2][rowb][lk * 8];
                #pragma unroll
                for (int fi = 0; fi < 4; ++fi) {
                    f32x4 a = acc[fi][fj];
                    a = __builtin_amdgcn_mfma_f32_16x16x32_bf16(A0[fi], B0, a, 0, 0, 0);
                    a = __builtin_amdgcn_mfma_f32_16x16x32_bf16(A0[fi], B1, a, 0, 0, 0);
                    a = __builtin_amdgcn_mfma_f32_16x16x32_bf16(A1[fi], B0, a, 0, 0, 0);
                    a = __builtin_amdgcn_mfma_f32_16x16x32_bf16(A1[fi], B1, a, 0, 0, 0);
                    a = __builtin_amdgcn_mfma_f32_16x16x32_bf16(A0[fi], B2, a, 0, 0, 0);
                    a = __builtin_amdgcn_mfma_f32_16x16x32_bf16(A2[fi], B0, a, 0, 0, 0);
                    acc[fi][fj] = a;
                }
            }
        }

        // ---- fold chunk into running argmin (qn dropped: constant per row) ----
        #pragma unroll
        for (int fj = 0; fj < 4; ++fj) {
            float cnv  = cnl[wc * 64 + fj * 16 + lrow];
            int   ploc = ch * PC + wc * 64 + fj * 16 + lrow;
            #pragma unroll
            for (int fi = 0; fi < 4; ++fi)
                #pragma unroll
                for (int r = 0; r < 4; ++r) {
                    float dist = cnv - 2.0f * acc[fi][fj][r];
                    if (dist < bestv[fi][r]) { bestv[fi][r] = dist; besti[fi][r] = ploc; }
                }
        }
    }

    // ---- butterfly over the 16 proto-lanes ----
    #pragma unroll
    for (int fi = 0; fi < 4; ++fi)
        #pragma unroll
        for (int r = 0; r < 4; ++r) {
            float v = bestv[fi][r]; int ix = besti[fi][r];
            #pragma unroll
            for (int off = 1; off < 16; off <<= 1) {
                float v2 = __shfl_xor(v, off, 64);
                int  ix2 = __shfl_xor(ix, off, 64);
                if (v2 < v || (v2 == v && ix2 < ix)) { v = v2; ix = ix2; }
            }
            bestv[fi][r] = v; besti[fi][r] = ix;
        }

    // ---- cross-wave (proto halves) combine ----
    if (wc == 1 && lrow == 0) {
        #pragma unroll
        for (int fi = 0; fi < 4; ++fi)
            #pragma unroll
            for (int r = 0; r < 4; ++r) {
                int rl = wr * 64 + fi * 16 + lk * 4 + r;
                vbuf[rl] = bestv[fi][r]; ibuf[rl] = besti[fi][r];
            }
    }
    __syncthreads();
    if (wc == 0 && lrow == 0) {
        #pragma unroll
        for (int fi = 0; fi < 4; ++fi)
            #pragma unroll
            for (int r = 0; r < 4; ++r) {
                int rl = wr * 64 + fi * 16 + lk * 4 + r;
                float v = bestv[fi][r]; int ix = besti[fi][r];
                float v2 = vbuf[rl];    int i2 = ibuf[rl];
                if (v2 < v || (v2 == v && i2 < ix)) { v = v2; ix = i2; }
                bp[rl] = ix;
                out[(size_t)IDX_OFF + (size_t)(bn0 + rl) * NBLK + m] =
                    (float)(m * NPROTO + ix);
            }
    }
    __syncthreads();

    // ---- epilogue: emb copy (exact f32) + commitment partial ----
    {
        int row = t >> 1, hf = t & 1;
        const float* cv = mem + ((size_t)(m * NPROTO + bp[row])) * DB + hf * 64;
        const float* qv = q + (size_t)(bn0 + row) * DM + m * DB + hf * 64;
        float*       ov = out + (size_t)(bn0 + row) * DM + m * DB + hf * 64;
        float lacc = 0.f;
        #pragma unroll
        for (int j = 0; j < 4; ++j) {
            float4 c4 = *(const float4*)(cv + j * 16);
            float4 q4 = *(const float4*)(qv + j * 16);
            *(float4*)(ov + j * 16) = c4;
            float dx = c4.x - q4.x, dy = c4.y - q4.y;
            float dz = c4.z - q4.z, dw = c4.w - q4.w;
            lacc += dx * dx + dy * dy + dz * dz + dw * dw;
        }
        red[t] = lacc;
    }
    __syncthreads();
    for (int sred = 128; sred > 0; sred >>= 1) {
        if (t < sred) red[t] += red[t + sred];
        __syncthreads();
    }
    if (t == 0) partials[blockIdx.y * gridDim.x + blockIdx.x] = red[0];
}

// ================= fallback f32 kernel (used if ws too small) =================
__global__ __launch_bounds__(256, 1) void vq_main_f32(const float* __restrict__ q,
                                                      const float* __restrict__ mem,
                                                      const float* __restrict__ cn,
                                                      float* __restrict__ out,
                                                      float* __restrict__ partials) {
    __shared__ float q_lds[TM * 132];
    __shared__ float c_lds[TM * 132];
    __shared__ float red[256];

    const int t    = threadIdx.x;
    const int tile = blockIdx.x;
    const int m    = blockIdx.y;
    const int tr   = t >> 4;
    const int tc   = t & 15;
    const int bn0  = tile * TM;

    const float* qbase = q + (size_t)bn0 * DM + m * DB;
    #pragma unroll
    for (int it = 0; it < 16; ++it) {
        int idx = it * 256 + t;
        int row = idx >> 5;
        int c4  = (idx & 31) << 2;
        *(float4*)&q_lds[row * 132 + c4] = *(const float4*)(qbase + (size_t)row * DM + c4);
    }

    float bestv[8]; int besti[8];
    #pragma unroll
    for (int i = 0; i < 8; ++i) { bestv[i] = 3.4e38f; besti[i] = 0; }
    const float* cbase = mem + (size_t)m * NPROTO * DB;

    for (int ch = 0; ch < 4; ++ch) {
        __syncthreads();
        const float* cb = cbase + (size_t)ch * PC * DB;
        #pragma unroll
        for (int it = 0; it < 16; ++it) {
            int idx = it * 256 + t;
            int row = idx >> 5;
            int c4  = (idx & 31) << 2;
            *(float4*)&c_lds[row * 132 + c4] = *(const float4*)(cb + row * DB + c4);
        }
        __syncthreads();

        float acc[8][8];
        #pragma unroll
        for (int i = 0; i < 8; ++i)
            #pragma unroll
            for (int j = 0; j < 8; ++j) acc[i][j] = 0.f;

        for (int d4 = 0; d4 < DB; d4 += 4) {
            float4 qa[8], cvv[8];
            #pragma unroll
            for (int i = 0; i < 8; ++i) qa[i] = *(const float4*)&q_lds[(tr + 16 * i) * 132 + d4];
            #pragma unroll
            for (int j = 0; j < 8; ++j) cvv[j] = *(const float4*)&c_lds[(tc + 16 * j) * 132 + d4];
            #pragma unroll
            for (int i = 0; i < 8; ++i)
                #pragma unroll
                for (int j = 0; j < 8; ++j) {
                    acc[i][j] += qa[i].x * cvv[j].x; acc[i][j] += qa[i].y * cvv[j].y;
                    acc[i][j] += qa[i].z * cvv[j].z; acc[i][j] += qa[i].w * cvv[j].w;
                }
        }
        #pragma unroll
        for (int i = 0; i < 8; ++i)
            #pragma unroll
            for (int j = 0; j < 8; ++j) {
                int lp = ch * PC + tc + 16 * j;
                float dist = cn[m * NPROTO + lp] - 2.0f * acc[i][j];
                if (dist < bestv[i]) { bestv[i] = dist; besti[i] = lp; }
            }
    }

    #pragma unroll
    for (int i = 0; i < 8; ++i) {
        float v = bestv[i]; int ix = besti[i];
        #pragma unroll
        for (int off = 1; off < 16; off <<= 1) {
            float v2 = __shfl_xor(v, off, 64);
            int  ix2 = __shfl_xor(ix, off, 64);
            if (v2 < v || (v2 == v && ix2 < ix)) { v = v2; ix = ix2; }
        }
        bestv[i] = v; besti[i] = ix;
    }

    float lacc = 0.f;
    #pragma unroll
    for (int i = 0; i < 8; ++i) {
        int row = tr + 16 * i;
        int bn  = bn0 + row;
        const float* cvec = cbase + (size_t)besti[i] * DB;
        float* orow = out + (size_t)bn * DM + m * DB;
        #pragma unroll
        for (int h = 0; h < 2; ++h) {
            int col = h * 64 + tc * 4;
            float4 c4v = *(const float4*)(cvec + col);
            *(float4*)(orow + col) = c4v;
            float4 qv2 = *(const float4*)&q_lds[row * 132 + col];
            float dx = c4v.x - qv2.x, dy = c4v.y - qv2.y;
            float dz = c4v.z - qv2.z, dw = c4v.w - qv2.w;
            lacc += dx * dx + dy * dy + dz * dz + dw * dw;
        }
        if (tc == 0)
            out[(size_t)IDX_OFF + (size_t)bn * NBLK + m] = (float)(m * NPROTO + besti[i]);
    }

    red[t] = lacc;
    __syncthreads();
    for (int s = 128; s > 0; s >>= 1) {
        if (t < s) red[t] += red[t + s];
        __syncthreads();
    }
    if (t == 0) partials[blockIdx.y * gridDim.x + blockIdx.x] = red[0];
}

__global__ __launch_bounds__(256) void vq_final(const float* __restrict__ partials,
                                                float* __restrict__ out) {
    __shared__ float red[256];
    int t = threadIdx.x;
    red[t] = partials[t] + partials[t + 256];
    __syncthreads();
    for (int s = 128; s > 0; s >>= 1) {
        if (t < s) red[t] += red[t + s];
        __syncthreads();
    }
    if (t == 0) {
        out[VQ_OFF] = 0.f;
        out[CL_OFF] = red[0] / 8388608.0f;
    }
}

extern "C" void kernel_launch(void* const* d_in, const int* in_sizes, int n_in,
                              void* d_out, int out_size, void* d_ws, size_t ws_size,
                              hipStream_t stream) {
    const float* q   = (const float*)d_in[0];
    const float* mem = (const float*)d_in[1];
    float* out = (float*)d_out;
    char* ws = (char*)d_ws;

    if (ws_size >= (size_t)WS_NEED) {
        u16* qh = (u16*)(ws + QHI_B);
        u16* qm = (u16*)(ws + QMI_B);
        u16* ql = (u16*)(ws + QLO_B);
        u16* ch_ = (u16*)(ws + CHI_B);
        u16* cm_ = (u16*)(ws + CMI_B);
        u16* cl_ = (u16*)(ws + CLO_B);
        float* cn = (float*)(ws + CN_B);
        float* partials = (float*)(ws + PART_B);

        split_planes<<<8192, 256, 0, stream>>>(q, qh, qm, ql);
        split_planes<<<512, 256, 0, stream>>>(mem, ch_, cm_, cl_);
        vq_init<<<16, 256, 0, stream>>>(mem, cn);
        dim3 grid(64, 8);
        vq_main_mfma<<<grid, 256, 0, stream>>>(q, mem, qh, qm, ql, ch_, cm_, cl_,
                                               cn, out, partials);
        vq_final<<<1, 256, 0, stream>>>(partials, out);
    } else {
        float* cn = (float*)ws;
        float* partials = cn + 4096;
        vq_init<<<16, 256, 0, stream>>>(mem, cn);
        dim3 grid(64, 8);
        vq_main_f32<<<grid, 256, 0, stream>>>(q, mem, cn, out, partials);
        vq_final<<<1, 256, 0, stream>>>(partials, out);
    }
}